// Round 5
// baseline (348.728 us; speedup 1.0000x reference)
//
#include <hip/hip_runtime.h>
#include <stdint.h>

typedef unsigned short ushort_t;
typedef __attribute__((ext_vector_type(8))) short short8;
typedef __attribute__((ext_vector_type(8))) unsigned short ushort8;
typedef __attribute__((ext_vector_type(16))) float f32x16;

#define TOK 8192
#define DIM_IN 4096
#define DIM_OUT 4096
#define RANK 64
#define NT (DIM_IN / 64)   // 64 K-tiles of BK=64

// fp32 -> bf16 round-to-nearest-even
__device__ __forceinline__ ushort_t f2bf(float f) {
    unsigned u = __float_as_uint(f);
    unsigned r = (u + 0x7fffu + ((u >> 16) & 1u)) >> 16;
    return (ushort_t)r;
}

__device__ __forceinline__ void gload16(const void* g, void* l) {
    __builtin_amdgcn_global_load_lds(
        (const __attribute__((address_space(1))) unsigned int*)g,
        (__attribute__((address_space(3))) unsigned int*)l,
        16, 0, 0);
}

// ---------------- Kernel 1: input fp32 -> bf16 ----------------
__global__ __launch_bounds__(256) void prep_input_k(const float* __restrict__ in,
                                                    ushort_t* __restrict__ out) {
    size_t idx = (size_t)blockIdx.x * 256 + threadIdx.x;
    const float4* p = (const float4*)(in + idx * 8);
    float4 f0 = p[0], f1 = p[1];
    ushort8 o;
    o[0] = f2bf(f0.x); o[1] = f2bf(f0.y); o[2] = f2bf(f0.z); o[3] = f2bf(f0.w);
    o[4] = f2bf(f1.x); o[5] = f2bf(f1.y); o[6] = f2bf(f1.z); o[7] = f2bf(f1.w);
    *(ushort8*)(out + idx * 8) = o;
}

// ---------------- Kernel 2: W_eff = dequant(Wq,scale) + U*diag(s)*V^T -> bf16 ----------------
__global__ __launch_bounds__(256) void prep_weight_k(const float* __restrict__ wq,
                                                     const float* __restrict__ scale,
                                                     const float* __restrict__ U,
                                                     const float* __restrict__ s,
                                                     const float* __restrict__ V,
                                                     ushort_t* __restrict__ Wb) {
    __shared__ float Us[128][64];
    __shared__ float Vs[128][64];
    int tid = threadIdx.x;
    int ob = blockIdx.x >> 5;
    int kb = blockIdx.x & 31;

#pragma unroll
    for (int j = 0; j < 8; ++j) {
        int c = j * 256 + tid;
        int row = c >> 4;
        int col = (c & 15) * 4;
        float4 u = *(const float4*)&U[(size_t)(ob * 128 + row) * RANK + col];
        float4 sv = *(const float4*)&s[col];
        u.x *= sv.x; u.y *= sv.y; u.z *= sv.z; u.w *= sv.w;
        *(float4*)&Us[row][col] = u;
        float4 v = *(const float4*)&V[(size_t)(kb * 128 + row) * RANK + col];
        *(float4*)&Vs[row][col] = v;
    }
    __syncthreads();

    int ty = tid >> 4, tx = tid & 15;
    float acc[8][8];
#pragma unroll
    for (int i = 0; i < 8; ++i)
#pragma unroll
        for (int j = 0; j < 8; ++j) acc[i][j] = 0.f;

#pragma unroll 4
    for (int r4 = 0; r4 < 16; ++r4) {
        float4 u[8], v[8];
#pragma unroll
        for (int i = 0; i < 8; ++i) u[i] = *(const float4*)&Us[ty * 8 + i][r4 * 4];
#pragma unroll
        for (int j = 0; j < 8; ++j) v[j] = *(const float4*)&Vs[tx * 8 + j][r4 * 4];
#pragma unroll
        for (int i = 0; i < 8; ++i)
#pragma unroll
            for (int j = 0; j < 8; ++j)
                acc[i][j] += u[i].x * v[j].x + u[i].y * v[j].y + u[i].z * v[j].z + u[i].w * v[j].w;
    }

#pragma unroll
    for (int i = 0; i < 8; ++i) {
        int o = ob * 128 + ty * 8 + i;
        int k0 = kb * 128 + tx * 8;
        float sc = scale[(size_t)o * (DIM_IN / 32) + (k0 >> 5)];
        float4 q0 = *(const float4*)&wq[(size_t)o * DIM_IN + k0];
        float4 q1 = *(const float4*)&wq[(size_t)o * DIM_IN + k0 + 4];
        ushort8 w;
        w[0] = f2bf(q0.x * sc + acc[i][0]);
        w[1] = f2bf(q0.y * sc + acc[i][1]);
        w[2] = f2bf(q0.z * sc + acc[i][2]);
        w[3] = f2bf(q0.w * sc + acc[i][3]);
        w[4] = f2bf(q1.x * sc + acc[i][4]);
        w[5] = f2bf(q1.y * sc + acc[i][5]);
        w[6] = f2bf(q1.z * sc + acc[i][6]);
        w[7] = f2bf(q1.w * sc + acc[i][7]);
        *(ushort8*)&Wb[(size_t)o * DIM_IN + k0] = w;
    }
}

// ---------------- Kernel 3: 256^2 GEMM via mfma_f32_32x32x16_bf16 ----------------
// 512 threads (8 waves, 2M x 4N), BK=64, st_16x32-swizzled LDS (same staging as r4;
// only the reader changed). Per wave: 128x64 output = 4 rowblocks(32) x 2 nf(32) of
// 32x32 frags, acc = 8 x f32x16 = 128 AGPR. 32 MFMA/tile (vs 64) at the 2382-TF
// 32x32 rate. Phases (m01 n0)(m01 n1)(m23 n1)(m23 n0), reads one segment ahead,
// barriers only at B-drain / A-drain / tile-end(+vmcnt(6)).
// Swizzle note: frag k-step bit5 collides with the st_16x32 XOR bit -> per-lane
// base pair lof0 / lof1 = lof0 ^ 16 selected per k-step at compile time.
__global__ __launch_bounds__(512, 2) void gemm_k(const ushort_t* __restrict__ A,
                                                 const ushort_t* __restrict__ B,
                                                 const float* __restrict__ bias,
                                                 float* __restrict__ C) {
    __shared__ ushort_t lds[2][2][2][8192];

    const int tid = threadIdx.x;
    const int wid = tid >> 6;
    const int lane = tid & 63;

    // XCD-aware bijective swizzle: 512 blocks, 8 XCDs, 64 per XCD
    int bid = blockIdx.x;
    int swz = (bid & 7) * 64 + (bid >> 3);
    const int bm = swz >> 4;   // 32 M-tiles
    const int bn = swz & 15;   // 16 N-tiles

    const int wr = wid >> 2;   // 0..1 (M)
    const int wc = wid & 3;    // 0..3 (N)

    // --- staging: wave wid fills subtiles {wid, wid+8} of each 128x64 half-tile.
    const int lane2 = lane ^ (((lane >> 5) & 1) << 1);
    const int srow = (wid >> 1) * 16 + (lane2 >> 2);
    const int scol = (wid & 1) * 32 + (lane2 & 3) * 8;
    const ushort_t* pa = A + (size_t)(bm * 256 + srow) * DIM_IN + scol;
    const ushort_t* pb = B + (size_t)(bn * 256 + srow) * DIM_IN + scol;

    // --- 32x32x16 fragment read base (elem units), swizzle-folded:
    // row = lane&31 (subtile row lane&15, row-half (lane>>4)&1), k-lane-off (lane>>5)*8,
    // XOR bit5 by row-bit3. lof1 = lof0 ^ 16 handles odd k-steps (bit5 collision).
    const int lane_byte = (lane & 15) * 64 + ((lane >> 4) & 1) * 2048 +
                          (((lane >> 5) * 16) ^ (((lane >> 3) & 1) << 5));
    const int lof0 = lane_byte >> 1;
    const int lof1 = lof0 ^ 16;

    f32x16 acc[4][2] = {};   // [rowblock32][nf]

    auto stageA = [&](int buf, int half, int t) {
        const ushort_t* g = pa + (size_t)half * 128 * DIM_IN + t * 64;
        gload16(g, &lds[buf][0][half][wid * 512]);
        gload16(g + (size_t)64 * DIM_IN, &lds[buf][0][half][(wid + 8) * 512]);
    };
    auto stageB = [&](int buf, int half, int t) {
        const ushort_t* g = pb + (size_t)half * 128 * DIM_IN + t * 64;
        gload16(g, &lds[buf][1][half][wid * 512]);
        gload16(g + (size_t)64 * DIM_IN, &lds[buf][1][half][(wid + 8) * 512]);
    };

    // mode: 2 = steady state; 1 = t=NT-2 (only P0 stage, vmcnt(0)); 0 = last tile
    auto tile_step = [&](int buf, int t, int mode) {
        const ushort_t* LA = &lds[buf][0][wr][0];
        const ushort_t* LB = &lds[buf][1][wc >> 1][0];
        const int rb = (wc & 1) * 2;      // B rowblock base within 128-row half
        short8 a[2][4], b0[4], b1[4];     // a: [mf][ks] for current m-half

        auto rdA = [&](int h, int mf, int ks) {
            a[mf][ks] = *(const short8*)(LA + (2 * h + mf) * 2048 + (ks >> 1) * 512 +
                                         ((ks & 1) ? lof1 : lof0));
        };
        auto rdB = [&](short8(&bb)[4], int nf, int ks) {
            bb[ks] = *(const short8*)(LB + (rb + nf) * 2048 + (ks >> 1) * 512 +
                                      ((ks & 1) ? lof1 : lof0));
        };
        // 4 MFMA: rowblocks {mbase, mbase+1} x nf, k-steps {ks0, ks0+1}
        auto cluster = [&](int mbase, int nf, short8(&bb)[4], int ks0) {
            __builtin_amdgcn_s_setprio(1);
#pragma unroll
            for (int kk = 0; kk < 2; ++kk)
#pragma unroll
                for (int mf = 0; mf < 2; ++mf)
                    acc[mbase + mf][nf] = __builtin_amdgcn_mfma_f32_32x32x16_bf16(
                        a[mf][ks0 + kk], bb[ks0 + kk], acc[mbase + mf][nf], 0, 0, 0);
            __builtin_amdgcn_s_setprio(0);
        };

        // ---- PH0 (m01 x n0): cluster0 operands first, then rest
        rdA(0, 0, 0); rdA(0, 1, 0); rdA(0, 0, 1); rdA(0, 1, 1);
        rdB(b0, 0, 0); rdB(b0, 0, 1);
        rdA(0, 0, 2); rdA(0, 1, 2); rdA(0, 0, 3); rdA(0, 1, 3);
        rdB(b0, 0, 2); rdB(b0, 0, 3);
        if (mode >= 1) stageA(buf ^ 1, 1, t + 1);
        cluster(0, 0, b0, 0);            // seg0
        rdB(b1, 1, 0); rdB(b1, 1, 1);    // seg2 operands
        cluster(0, 0, b0, 2);            // seg1

        // ---- PH1 (m01 x n1)
        rdB(b1, 1, 2); rdB(b1, 1, 3);    // seg3 operands
        cluster(0, 1, b1, 0);            // seg2 (last use a[.][0..1] of m01)
        rdA(1, 0, 0); rdA(1, 1, 0); rdA(1, 0, 1); rdA(1, 1, 1);  // m23 ks01 (WAR ok)
        cluster(0, 1, b1, 2);            // seg3 (last use a[.][2..3] of m01)
        __builtin_amdgcn_s_barrier();    // P1-end: all waves' B(t) reads complete

        // ---- PH2 (m23 x n1): B region restageable
        rdA(1, 0, 2); rdA(1, 1, 2); rdA(1, 0, 3); rdA(1, 1, 3);  // m23 ks23
        if (mode == 2) { stageB(buf, 0, t + 2); stageB(buf, 1, t + 2); }
        cluster(2, 1, b1, 0);            // seg4
        cluster(2, 1, b1, 2);            // seg5 (last use b1)
        __builtin_amdgcn_s_barrier();    // P2-end: all waves' A(t) reads complete

        // ---- PH3 (m23 x n0): A region restageable; no reads
        if (mode == 2) stageA(buf, 0, t + 2);
        cluster(2, 0, b0, 0);            // seg6
        cluster(2, 0, b0, 2);            // seg7
        if (mode == 2)
            asm volatile("s_waitcnt vmcnt(6)" ::: "memory");   // tile t+1 fully landed
        else if (mode == 1)
            asm volatile("s_waitcnt vmcnt(0)" ::: "memory");   // tail drain
        if (mode >= 1) __builtin_amdgcn_s_barrier();           // tile-end
    };

    // ---- prologue: tile0 (4 halves) + tile1 (B0,B1,A0); A1(t1) staged at t0.PH0
    stageA(0, 0, 0); stageA(0, 1, 0); stageB(0, 0, 0); stageB(0, 1, 0);
    stageB(1, 0, 1); stageB(1, 1, 1); stageA(1, 0, 1);
    asm volatile("s_waitcnt vmcnt(6)" ::: "memory");           // tile0 landed
    __builtin_amdgcn_s_barrier();

    for (int t = 0; t < NT - 2; t += 2) {
        tile_step(0, t, 2);
        tile_step(1, t + 1, 2);
    }
    tile_step(0, NT - 2, 1);
    tile_step(1, NT - 1, 0);

    // ---- epilogue: 32x32 C/D layout: col = lane&31, row = (reg&3)+8*(reg>>2)+4*(lane>>5)
    const int ccol = lane & 31;
    const int crow4 = 4 * (lane >> 5);
#pragma unroll
    for (int nf = 0; nf < 2; ++nf) {
        int gcol = bn * 256 + wc * 64 + nf * 32 + ccol;
        float bv = bias[gcol];
#pragma unroll
        for (int rb4 = 0; rb4 < 4; ++rb4) {
            size_t grow0 = (size_t)(bm * 256 + wr * 128 + rb4 * 32 + crow4);
#pragma unroll
            for (int reg = 0; reg < 16; ++reg) {
                size_t grow = grow0 + (reg & 3) + 8 * (reg >> 2);
                C[grow * DIM_OUT + gcol] = acc[rb4][nf][reg] + bv;
            }
        }
    }
}

extern "C" void kernel_launch(void* const* d_in, const int* in_sizes, int n_in,
                              void* d_out, int out_size, void* d_ws, size_t ws_size,
                              hipStream_t stream) {
    const float* input = (const float*)d_in[0];
    const float* wq    = (const float*)d_in[1];
    const float* scale = (const float*)d_in[2];
    const float* bias  = (const float*)d_in[3];
    const float* U     = (const float*)d_in[4];
    const float* s     = (const float*)d_in[5];
    const float* V     = (const float*)d_in[6];
    float* out = (float*)d_out;

    ushort_t* Abf = (ushort_t*)d_ws;                       // 8192*4096*2 = 64 MB
    ushort_t* Wbf = Abf + (size_t)TOK * DIM_IN;            // 4096*4096*2 = 32 MB

    prep_input_k<<<(TOK * DIM_IN) / (256 * 8), 256, 0, stream>>>(input, Abf);
    prep_weight_k<<<(DIM_OUT / 128) * (DIM_IN / 128), 256, 0, stream>>>(wq, scale, U, s, V, Wbf);
    gemm_k<<<(TOK / 256) * (DIM_OUT / 256), 512, 0, stream>>>(Abf, Wbf, bias, out);
}

// Round 6
// 285.671 us; speedup vs baseline: 1.2207x; 1.2207x over previous
//
#include <hip/hip_runtime.h>
#include <stdint.h>

typedef unsigned short ushort_t;
typedef __attribute__((ext_vector_type(8))) short short8;
typedef __attribute__((ext_vector_type(4))) unsigned short ushort4_t;
typedef __attribute__((ext_vector_type(8))) unsigned short ushort8;
typedef __attribute__((ext_vector_type(4))) float f32x4;

#define TOK 8192
#define DIM_IN 4096
#define DIM_OUT 4096
#define RANK 64
#define NT (DIM_IN / 64)   // 64 K-tiles of BK=64

// fp32 -> bf16 round-to-nearest-even
__device__ __forceinline__ ushort_t f2bf(float f) {
    unsigned u = __float_as_uint(f);
    unsigned r = (u + 0x7fffu + ((u >> 16) & 1u)) >> 16;
    return (ushort_t)r;
}
__device__ __forceinline__ float bf2f(ushort_t u) {
    return __uint_as_float(((unsigned)u) << 16);
}

__device__ __forceinline__ void gload16(const void* g, void* l) {
    __builtin_amdgcn_global_load_lds(
        (const __attribute__((address_space(1))) unsigned int*)g,
        (__attribute__((address_space(3))) unsigned int*)l,
        16, 0, 0);
}

// ---------------- Kernel 1: input fp32 -> bf16 ----------------
__global__ __launch_bounds__(256) void prep_input_k(const float* __restrict__ in,
                                                    ushort_t* __restrict__ out) {
    size_t idx = (size_t)blockIdx.x * 256 + threadIdx.x;
    const float4* p = (const float4*)(in + idx * 8);
    float4 f0 = p[0], f1 = p[1];
    ushort8 o;
    o[0] = f2bf(f0.x); o[1] = f2bf(f0.y); o[2] = f2bf(f0.z); o[3] = f2bf(f0.w);
    o[4] = f2bf(f1.x); o[5] = f2bf(f1.y); o[6] = f2bf(f1.z); o[7] = f2bf(f1.w);
    *(ushort8*)(out + idx * 8) = o;
}

// ---------------- Kernel 2: W_eff = dequant(Wq,scale) + U*diag(s)*V^T -> bf16 ----------------
// MFMA version: per 128x128 tile, compute svd = (U*s)[128x64] @ V[128x64]^T with
// bf16 16x16x32 MFMA (4 waves, 64x64 out each), round svd to bf16 through LDS,
// then a coalesced merge pass: out = wq*scale + svd (ushort8 stores).
// LDS plan (36 KiB): stage phase U'=[0..8192) V'=[8192..16384) bf16, XOR-swizzled
// byte^=(row&7)<<4; merge phase W_svd = [128][136] ushort over the same memory.
__global__ __launch_bounds__(256) void prep_weight_k(const float* __restrict__ wq,
                                                     const float* __restrict__ scale,
                                                     const float* __restrict__ U,
                                                     const float* __restrict__ s,
                                                     const float* __restrict__ V,
                                                     ushort_t* __restrict__ Wb) {
    __shared__ ushort_t sm[18432];   // 36 KiB
    const int tid = threadIdx.x;
    const int wv = tid >> 6;
    const int lane = tid & 63;
    const int ob = blockIdx.x >> 5;
    const int kb = blockIdx.x & 31;

    // ---- stage U' = U*s and V' = V as bf16, swizzled (byte ^= (row&7)<<4)
    char* smb = (char*)sm;
#pragma unroll
    for (int j = 0; j < 8; ++j) {
        int idx = j * 256 + tid;          // 0..2047 float4 slots
        int row = idx >> 4;               // 0..127
        int c4 = idx & 15;                // float4 col index (cols c4*4)
        float4 sv = *(const float4*)&s[c4 * 4];
        float4 u = *(const float4*)&U[(size_t)(ob * 128 + row) * RANK + c4 * 4];
        ushort4_t up;
        up[0] = f2bf(u.x * sv.x); up[1] = f2bf(u.y * sv.y);
        up[2] = f2bf(u.z * sv.z); up[3] = f2bf(u.w * sv.w);
        int wbyte = row * 128 + ((c4 * 8) ^ ((row & 7) << 4));
        *(ushort4_t*)(smb + wbyte) = up;
        float4 v = *(const float4*)&V[(size_t)(kb * 128 + row) * RANK + c4 * 4];
        ushort4_t vp;
        vp[0] = f2bf(v.x); vp[1] = f2bf(v.y); vp[2] = f2bf(v.z); vp[3] = f2bf(v.w);
        *(ushort4_t*)(smb + 16384 + wbyte) = vp;
    }
    __syncthreads();

    // ---- MFMA: wave wv -> out quadrant (wr = wv>>1)*64 rows, (wc = wv&1)*64 cols
    const int wr = wv >> 1, wc = wv & 1;
    f32x4 acc[4][4] = {};
    {
        short8 a[4], b[4];
#pragma unroll
        for (int kk = 0; kk < 2; ++kk) {
#pragma unroll
            for (int f = 0; f < 4; ++f) {
                int r = wr * 64 + f * 16 + (lane & 15);
                int kbyte = ((lane >> 4) * 16 + kk * 64) ^ ((r & 7) << 4);
                a[f] = *(const short8*)(smb + r * 128 + kbyte);
                int r2 = wc * 64 + f * 16 + (lane & 15);
                int kbyte2 = ((lane >> 4) * 16 + kk * 64) ^ ((r2 & 7) << 4);
                b[f] = *(const short8*)(smb + 16384 + r2 * 128 + kbyte2);
            }
#pragma unroll
            for (int fm = 0; fm < 4; ++fm)
#pragma unroll
                for (int fn = 0; fn < 4; ++fn)
                    acc[fm][fn] = __builtin_amdgcn_mfma_f32_16x16x32_bf16(
                        a[fm], b[fn], acc[fm][fn], 0, 0, 0);
        }
    }
    __syncthreads();   // all MFMA reads of U'/V' done before overwrite

    // ---- spill svd (bf16) to LDS as [128][136] ushort
    // C/D: col = lane&15 (k/fn axis), row = (lane>>4)*4 + reg (o/fm axis)
#pragma unroll
    for (int fm = 0; fm < 4; ++fm)
#pragma unroll
        for (int fn = 0; fn < 4; ++fn) {
            int row0 = wr * 64 + fm * 16 + (lane >> 4) * 4;
            int col = wc * 64 + fn * 16 + (lane & 15);
#pragma unroll
            for (int r = 0; r < 4; ++r)
                sm[(row0 + r) * 136 + col] = f2bf(acc[fm][fn][r]);
        }
    __syncthreads();

    // ---- merge: out = wq*scale + svd, coalesced ushort8 stores
    const int ty = tid >> 4, tx = tid & 15;
#pragma unroll
    for (int i = 0; i < 8; ++i) {
        int ol = ty * 8 + i;
        int o = ob * 128 + ol;
        int k0 = kb * 128 + tx * 8;
        float sc = scale[(size_t)o * (DIM_IN / 32) + (k0 >> 5)];
        float4 q0 = *(const float4*)&wq[(size_t)o * DIM_IN + k0];
        float4 q1 = *(const float4*)&wq[(size_t)o * DIM_IN + k0 + 4];
        ushort8 sv8 = *(const ushort8*)&sm[ol * 136 + tx * 8];
        ushort8 w;
        w[0] = f2bf(q0.x * sc + bf2f(sv8[0]));
        w[1] = f2bf(q0.y * sc + bf2f(sv8[1]));
        w[2] = f2bf(q0.z * sc + bf2f(sv8[2]));
        w[3] = f2bf(q0.w * sc + bf2f(sv8[3]));
        w[4] = f2bf(q1.x * sc + bf2f(sv8[4]));
        w[5] = f2bf(q1.y * sc + bf2f(sv8[5]));
        w[6] = f2bf(q1.z * sc + bf2f(sv8[6]));
        w[7] = f2bf(q1.w * sc + bf2f(sv8[7]));
        *(ushort8*)&Wb[(size_t)o * DIM_IN + k0] = w;
    }
}

// ---------------- Kernel 3: 256^2 GEMM, C = A @ B^T + bias (r4 proven version) ----------------
// 512 threads (8 waves, 2M x 4N), BK=64, st_16x32-swizzled LDS, counted vmcnt(6).
// Tile = 8 segments of 8 MFMA; reads issued one segment ahead. Barriers only at
// B-drain / A-drain / tile-end(+vmcnt).
__global__ __launch_bounds__(512, 2) void gemm_k(const ushort_t* __restrict__ A,
                                                 const ushort_t* __restrict__ B,
                                                 const float* __restrict__ bias,
                                                 float* __restrict__ C) {
    __shared__ ushort_t lds[2][2][2][8192];

    const int tid = threadIdx.x;
    const int wid = tid >> 6;
    const int lane = tid & 63;

    // XCD-aware bijective swizzle: 512 blocks, 8 XCDs, 64 per XCD
    int bid = blockIdx.x;
    int swz = (bid & 7) * 64 + (bid >> 3);
    const int bm = swz >> 4;   // 32 M-tiles
    const int bn = swz & 15;   // 16 N-tiles

    const int wr = wid >> 2;   // 0..1 (M)
    const int wc = wid & 3;    // 0..3 (N)

    // --- staging: wave wid fills subtiles {wid, wid+8} of each 128x64 half-tile.
    const int lane2 = lane ^ (((lane >> 5) & 1) << 1);
    const int srow = (wid >> 1) * 16 + (lane2 >> 2);
    const int scol = (wid & 1) * 32 + (lane2 & 3) * 8;
    const ushort_t* pa = A + (size_t)(bm * 256 + srow) * DIM_IN + scol;
    const ushort_t* pb = B + (size_t)(bn * 256 + srow) * DIM_IN + scol;

    // --- swizzled per-lane ds_read offset (element units)
    const int loff = ((((lane & 15) * 64 + (lane >> 4) * 16) ^ (((lane >> 3) & 1) << 5)) >> 1);

    f32x4 acc[8][4] = {};

    auto stageA = [&](int buf, int half, int t) {
        const ushort_t* g = pa + (size_t)half * 128 * DIM_IN + t * 64;
        gload16(g, &lds[buf][0][half][wid * 512]);
        gload16(g + (size_t)64 * DIM_IN, &lds[buf][0][half][(wid + 8) * 512]);
    };
    auto stageB = [&](int buf, int half, int t) {
        const ushort_t* g = pb + (size_t)half * 128 * DIM_IN + t * 64;
        gload16(g, &lds[buf][1][half][wid * 512]);
        gload16(g + (size_t)64 * DIM_IN, &lds[buf][1][half][(wid + 8) * 512]);
    };

    // mode: 2 = steady state; 1 = t=NT-2 (only P0 stage, vmcnt(0)); 0 = last tile
    auto tile_step = [&](int buf, int t, int mode) {
        const ushort_t* LA = &lds[buf][0][wr][0];
        const ushort_t* LB = &lds[buf][1][wc >> 1][0];
        const int bsub = (wc & 1) * 4;
        short8 aA[4], aB[4], bA[2][2], bB[2][2];

        auto rdA = [&](short8 (&dst)[4], int mhalf, int kk) {
#pragma unroll
            for (int m = 0; m < 4; ++m)
                dst[m] = *(const short8*)(LA + ((((mhalf * 4 + m) * 2) + kk) << 9) + loff);
        };
        auto rdB = [&](short8 (&dst)[2][2], int noff, int kk) {
#pragma unroll
            for (int n = 0; n < 2; ++n)
                dst[n][kk] = *(const short8*)(LB + ((((bsub + noff + n) * 2) + kk) << 9) + loff);
        };
        auto cluster = [&](short8 (&av)[4], short8 (&bv)[2][2], int kk, int mb, int nb) {
            __builtin_amdgcn_s_setprio(1);
#pragma unroll
            for (int m = 0; m < 4; ++m)
#pragma unroll
                for (int n = 0; n < 2; ++n)
                    acc[mb + m][nb + n] =
                        __builtin_amdgcn_mfma_f32_16x16x32_bf16(av[m], bv[n][kk], acc[mb + m][nb + n], 0, 0, 0);
            __builtin_amdgcn_s_setprio(0);
        };

        // ---- PH0 (m0-3 x n0-1): seg0+seg1 reads up front (tile-boundary exposure)
        rdA(aA, 0, 0);                 // seg0: a03 k0  [4]
        rdB(bA, 0, 0);                 // seg0: b01 k0  [2]
        rdA(aB, 0, 1);                 // seg1: a03 k1  [4]
        rdB(bA, 0, 1);                 // seg1: b01 k1  [2]
        if (mode >= 1) stageA(buf ^ 1, 1, t + 1);
        cluster(aA, bA, 0, 0, 0);      // seg0
        rdB(bB, 2, 0);                 // seg2 ops: b23 k0 [2]
        cluster(aB, bA, 1, 0, 0);      // seg1

        // ---- PH1 (m0-3 x n2-3)
        rdB(bB, 2, 1);                 // seg3 ops: b23 k1 [2]
        cluster(aA, bB, 0, 0, 2);      // seg2 (last use of a03 k0)
        rdA(aA, 1, 0);                 // seg4 ops: a47 k0 -> reuse aA (WAR after seg2)
        cluster(aB, bB, 1, 0, 2);      // seg3 (last use of a03 k1)
        __builtin_amdgcn_s_barrier();  // P1-end: all waves' B(t) reads complete

        // ---- PH2 (m4-7 x n2-3): B region of buf now safe to restage
        rdA(aB, 1, 1);                 // seg5 ops: a47 k1 -> reuse aB
        if (mode == 2) { stageB(buf, 0, t + 2); stageB(buf, 1, t + 2); }
        cluster(aA, bB, 0, 4, 2);      // seg4
        cluster(aB, bB, 1, 4, 2);      // seg5 (last use of b23)
        __builtin_amdgcn_s_barrier();  // P2-end: all waves' A(t) reads complete

        // ---- PH3 (m4-7 x n0-1): no reads; A region safe to restage
        if (mode == 2) stageA(buf, 0, t + 2);
        cluster(aA, bA, 0, 4, 0);      // seg6
        cluster(aB, bA, 1, 4, 0);      // seg7
        if (mode == 2)
            asm volatile("s_waitcnt vmcnt(6)" ::: "memory");   // tile t+1 fully landed
        else if (mode == 1)
            asm volatile("s_waitcnt vmcnt(0)" ::: "memory");   // tail drain
        if (mode >= 1) __builtin_amdgcn_s_barrier();           // tile-end
    };

    // ---- prologue: tile0 (4 halves) + tile1 (B0,B1,A0); A1(t1) staged at t0.P0
    stageA(0, 0, 0); stageA(0, 1, 0); stageB(0, 0, 0); stageB(0, 1, 0);
    stageB(1, 0, 1); stageB(1, 1, 1); stageA(1, 0, 1);
    asm volatile("s_waitcnt vmcnt(6)" ::: "memory");           // tile0 landed
    __builtin_amdgcn_s_barrier();

    for (int t = 0; t < NT - 2; t += 2) {
        tile_step(0, t, 2);
        tile_step(1, t + 1, 2);
    }
    tile_step(0, NT - 2, 1);
    tile_step(1, NT - 1, 0);

    // ---- epilogue: C/D layout col = lane&15, row = (lane>>4)*4 + reg
    const int ccol = lane & 15;
    const int crow = (lane >> 4) * 4;
#pragma unroll
    for (int n = 0; n < 4; ++n) {
        int gcol = bn * 256 + wc * 64 + n * 16 + ccol;
        float bv = bias[gcol];
#pragma unroll
        for (int m = 0; m < 8; ++m) {
            size_t grow = (size_t)(bm * 256 + wr * 128 + m * 16 + crow);
#pragma unroll
            for (int r = 0; r < 4; ++r)
                C[(grow + r) * DIM_OUT + gcol] = acc[m][n][r] + bv;
        }
    }
}

extern "C" void kernel_launch(void* const* d_in, const int* in_sizes, int n_in,
                              void* d_out, int out_size, void* d_ws, size_t ws_size,
                              hipStream_t stream) {
    const float* input = (const float*)d_in[0];
    const float* wq    = (const float*)d_in[1];
    const float* scale = (const float*)d_in[2];
    const float* bias  = (const float*)d_in[3];
    const float* U     = (const float*)d_in[4];
    const float* s     = (const float*)d_in[5];
    const float* V     = (const float*)d_in[6];
    float* out = (float*)d_out;

    ushort_t* Abf = (ushort_t*)d_ws;                       // 8192*4096*2 = 64 MB
    ushort_t* Wbf = Abf + (size_t)TOK * DIM_IN;            // 4096*4096*2 = 32 MB

    prep_input_k<<<(TOK * DIM_IN) / (256 * 8), 256, 0, stream>>>(input, Abf);
    prep_weight_k<<<(DIM_OUT / 128) * (DIM_IN / 128), 256, 0, stream>>>(wq, scale, U, s, V, Wbf);
    gemm_k<<<(TOK / 256) * (DIM_OUT / 256), 512, 0, stream>>>(Abf, Wbf, bias, out);
}